// Round 5
// baseline (1089.426 us; speedup 1.0000x reference)
//
#include <hip/hip_runtime.h>
#include <math.h>

#define E_DIM 1024
#define H_DIM 2048
#define R_DIM 1024
#define RULES 50000
#define GRID_BLOCKS 1024

// d_out layout: [out 50000][h 2048][c 2048][remainder_out 1024]
#define OUT_H  50000
#define OUT_C  52048
#define OUT_RO 54096

// ws layout (float offsets); every write is a fixed slot -> deterministic
#define WS_XP    0          // [8][1024]    x partials (rem @ W_rin)
#define WS_H     8192       // [2048]       h
#define WS_BSUM  10240      // [64]         per-block sum(exp(logit))
#define WS_CNT   10304      // [16] uints   barrier counters (reset kernel zeroes)
#define WS_PL    10320      // [32][50000]  logits partials
#define WS_PRO   1610320    // [32][1024]   remainder_out partials
// total ~1.64M floats ~6.6 MB

typedef float f32x4 __attribute__((ext_vector_type(4)));

__device__ __forceinline__ f32x4 nt4(const float* p) {
    return __builtin_nontemporal_load((const f32x4*)p);
}
__device__ __forceinline__ float sigf(float x) { return 1.f / (1.f + expf(-x)); }

// grid barrier: all GRID_BLOCKS blocks co-resident (4/CU by construction).
// release: threadfence flushes stores device-wide; acquire: threadfence after.
__device__ __forceinline__ void gbar(unsigned int* c, unsigned int target) {
    __threadfence();
    __syncthreads();
    if (threadIdx.x == 0) {
        __hip_atomic_fetch_add(c, 1u, __ATOMIC_RELEASE, __HIP_MEMORY_SCOPE_AGENT);
        while (__hip_atomic_load(c, __ATOMIC_RELAXED, __HIP_MEMORY_SCOPE_AGENT) < target)
            __builtin_amdgcn_s_sleep(2);
    }
    __syncthreads();
    __threadfence();
}

__global__ void k_reset(unsigned int* __restrict__ cnt) {
    if (threadIdx.x < 16) cnt[threadIdx.x] = 0u;
}

__global__ __launch_bounds__(256, 4) void mega(
    const int* __restrict__ ident, const float* __restrict__ rem,
    const float* __restrict__ h0, const float* __restrict__ c0,
    const float* __restrict__ emb, const float* __restrict__ W_rin,
    const float* __restrict__ b_rin, const float* __restrict__ W_ih,
    const float* __restrict__ W_hh, const float* __restrict__ b_ih,
    const float* __restrict__ b_hh, const float* __restrict__ W_ro,
    const float* __restrict__ b_ro, const float* __restrict__ W_out,
    const float* __restrict__ b_out, float* __restrict__ d_out,
    float* __restrict__ ws)
{
    const int bid = blockIdx.x, tid = threadIdx.x;
    float* xp   = ws + WS_XP;
    float* wsh  = ws + WS_H;
    float* bsum = ws + WS_BSUM;
    float* pl   = ws + WS_PL;
    float* pro  = ws + WS_PRO;
    unsigned int* cnt = (unsigned int*)(ws + WS_CNT);

    __shared__ float smem[1032];  // A: rs[128] | B: xs[1024]+gl[8] | C: hs[64] | D: red[256]

    // ---- Phase A: xp[rc][e] partials of rem @ W_rin (32 blocks: 4 ec x 8 rc)
    if (bid < 32) {
        int ec = bid & 3, rc = bid >> 2;
        if (tid < 128) smem[tid] = rem[rc * 128 + tid];
        __syncthreads();
        int e = ec * 256 + tid;
        const float* base = W_rin + (size_t)(rc * 128) * E_DIM + e;
        float acc = 0.f;
#pragma unroll 8
        for (int rr = 0; rr < 128; ++rr)
            acc = fmaf(smem[rr], __builtin_nontemporal_load(base + (size_t)rr * E_DIM), acc);
        xp[rc * E_DIM + e] = acc;
    }
    gbar(cnt + 0, GRID_BLOCKS);

    // ---- Phase B: LSTM, 2 hidden units per block (1024*2 = 2048 exact) -----
    {
        long long row = (long long)ident[0] * E_DIM;
        for (int e = tid; e < E_DIM; e += 256) {
            float s = 0.f;
#pragma unroll
            for (int rc = 0; rc < 8; ++rc) s += xp[rc * E_DIM + e];
            smem[e] = emb[row + e] + fmaxf(s + b_rin[e], 0.f);
        }
        __syncthreads();
        int w = tid >> 6, lane = tid & 63;
        const f32x4* x4 = (const f32x4*)smem;
        const f32x4* h4 = (const f32x4*)h0;
#pragma unroll
        for (int u = 0; u < 2; ++u) {
            int k = bid * 2 + u;
            int j = w * H_DIM + k;               // torch gate order i,f,g,o
            const float* Wi = W_ih + (size_t)j * E_DIM;
            const float* Wh = W_hh + (size_t)j * H_DIM;
            float acc = 0.f;
#pragma unroll
            for (int s = 0; s < 4; ++s) {        // E/4 = 256 float4 over 64 lanes
                int idx = s * 64 + lane;
                f32x4 wv = nt4(Wi + idx * 4), xv = x4[idx];
                acc += wv.x * xv.x + wv.y * xv.y + wv.z * xv.z + wv.w * xv.w;
            }
#pragma unroll
            for (int s = 0; s < 8; ++s) {        // H/4 = 512 float4
                int idx = s * 64 + lane;
                f32x4 wv = nt4(Wh + idx * 4), hv = h4[idx];
                acc += wv.x * hv.x + wv.y * hv.y + wv.z * hv.z + wv.w * hv.w;
            }
#pragma unroll
            for (int off = 32; off > 0; off >>= 1) acc += __shfl_xor(acc, off);
            if (lane == 0) smem[1024 + u * 4 + w] = acc + b_ih[j] + b_hh[j];
        }
        __syncthreads();
        if (tid < 2) {
            int k = bid * 2 + tid;
            float gi = smem[1024 + tid * 4 + 0], gf = smem[1024 + tid * 4 + 1];
            float gv = smem[1024 + tid * 4 + 2], go = smem[1024 + tid * 4 + 3];
            float c = sigf(gf) * c0[k] + sigf(gi) * tanhf(gv);
            float h = sigf(go) * tanhf(c);
            d_out[OUT_H + k] = h;
            d_out[OUT_C + k] = c;
            wsh[k] = h;
        }
    }
    gbar(cnt + 1, GRID_BLOCKS);

    // ---- Phase C: 832 single-round tiles. bid<800: logits (jb=bid%25 width
    //      2048, hc=bid/25 chunk of 64 h); bid in [800,832): ro (hc=bid-800) --
    if (bid < 832) {
        int hc = (bid < 800) ? (bid / 25) : (bid - 800);
        if (tid < 64) smem[tid] = wsh[hc * 64 + tid];
        __syncthreads();
        if (bid < 800) {
            int j0 = (bid % 25) * 2048 + tid * 8;
            if (j0 < RULES) {                    // RULES%8==0 -> full 8 valid
                f32x4 a0 = {0.f, 0.f, 0.f, 0.f}, a1 = {0.f, 0.f, 0.f, 0.f};
                const float* base = W_out + (size_t)(hc * 64) * RULES + j0;
#pragma unroll 8
                for (int hh = 0; hh < 64; ++hh) {
                    float hv = smem[hh];
                    f32x4 w0 = nt4(base + (size_t)hh * RULES);
                    f32x4 w1 = nt4(base + (size_t)hh * RULES + 4);
                    a0.x = fmaf(hv, w0.x, a0.x); a0.y = fmaf(hv, w0.y, a0.y);
                    a0.z = fmaf(hv, w0.z, a0.z); a0.w = fmaf(hv, w0.w, a0.w);
                    a1.x = fmaf(hv, w1.x, a1.x); a1.y = fmaf(hv, w1.y, a1.y);
                    a1.z = fmaf(hv, w1.z, a1.z); a1.w = fmaf(hv, w1.w, a1.w);
                }
                *(f32x4*)(pl + (size_t)hc * RULES + j0) = a0;
                *(f32x4*)(pl + (size_t)hc * RULES + j0 + 4) = a1;
            }
        } else {
            int j0 = tid * 4;
            f32x4 acc = {0.f, 0.f, 0.f, 0.f};
            const float* base = W_ro + (size_t)(hc * 64) * R_DIM + j0;
#pragma unroll 16
            for (int hh = 0; hh < 64; ++hh) {
                float hv = smem[hh];
                f32x4 wv = nt4(base + (size_t)hh * R_DIM);
                acc.x = fmaf(hv, wv.x, acc.x); acc.y = fmaf(hv, wv.y, acc.y);
                acc.z = fmaf(hv, wv.z, acc.z); acc.w = fmaf(hv, wv.w, acc.w);
            }
            *(f32x4*)(pro + (size_t)hc * R_DIM + j0) = acc;
        }
    }
    gbar(cnt + 2, GRID_BLOCKS);

    // ---- Phase D1: logits finalize + per-block sum(exp); block 49: ro ------
    f32x4 l = {0.f, 0.f, 0.f, 0.f};
    bool dvalid = false;
    if (bid < 49) {
        int j0 = bid * 1024 + tid * 4;
        dvalid = j0 < RULES;
        float se = 0.f;
        if (dvalid) {
            f32x4 s = {0.f, 0.f, 0.f, 0.f};
#pragma unroll
            for (int hc = 0; hc < 32; ++hc) {
                f32x4 p = *(const f32x4*)(pl + (size_t)hc * RULES + j0);
                s.x += p.x; s.y += p.y; s.z += p.z; s.w += p.w;
            }
            f32x4 b = *(const f32x4*)(b_out + j0);
            l.x = fmaxf(s.x + b.x, 0.f);
            l.y = fmaxf(s.y + b.y, 0.f);
            l.z = fmaxf(s.z + b.z, 0.f);
            l.w = fmaxf(s.w + b.w, 0.f);
            se = expf(l.x) + expf(l.y) + expf(l.z) + expf(l.w);
        }
        smem[tid] = se;
        __syncthreads();
        for (int off = 128; off > 0; off >>= 1) {
            if (tid < off) smem[tid] += smem[tid + off];
            __syncthreads();
        }
        if (tid == 0) bsum[bid] = smem[0];
    } else if (bid == 49) {
        int j0 = tid * 4;
        f32x4 s = {0.f, 0.f, 0.f, 0.f};
#pragma unroll
        for (int hc = 0; hc < 32; ++hc) {
            f32x4 p = *(const f32x4*)(pro + (size_t)hc * R_DIM + j0);
            s.x += p.x; s.y += p.y; s.z += p.z; s.w += p.w;
        }
        f32x4 b = *(const f32x4*)(b_ro + j0);
        f32x4 o;
        o.x = fmaxf(s.x + b.x, 0.f);
        o.y = fmaxf(s.y + b.y, 0.f);
        o.z = fmaxf(s.z + b.z, 0.f);
        o.w = fmaxf(s.w + b.w, 0.f);
        *(f32x4*)(d_out + OUT_RO + j0) = o;
    }
    gbar(cnt + 3, GRID_BLOCKS);

    // ---- Phase D2: lse (fixed order) + write log_softmax -------------------
    if (dvalid) {
        float ssum = 0.f;
#pragma unroll
        for (int i = 0; i < 49; ++i) ssum += bsum[i];   // fixed order: deterministic
        float lse = logf(ssum);
        int j0 = bid * 1024 + tid * 4;
        f32x4 o = {l.x - lse, l.y - lse, l.z - lse, l.w - lse};
        *(f32x4*)(d_out + j0) = o;
    }
}

extern "C" void kernel_launch(void* const* d_in, const int* in_sizes, int n_in,
                              void* d_out, int out_size, void* d_ws, size_t ws_size,
                              hipStream_t stream)
{
    const int*   ident = (const int*)  d_in[0];
    const float* rem   = (const float*)d_in[1];
    const float* h0    = (const float*)d_in[2];
    const float* c0    = (const float*)d_in[3];
    const float* emb   = (const float*)d_in[4];
    const float* W_rin = (const float*)d_in[5];
    const float* b_rin = (const float*)d_in[6];
    const float* W_ih  = (const float*)d_in[7];
    const float* W_hh  = (const float*)d_in[8];
    const float* b_ih  = (const float*)d_in[9];
    const float* b_hh  = (const float*)d_in[10];
    const float* W_ro  = (const float*)d_in[11];
    const float* b_ro  = (const float*)d_in[12];
    const float* W_out = (const float*)d_in[13];
    const float* b_out = (const float*)d_in[14];
    float* out = (float*)d_out;
    float* ws  = (float*)d_ws;
    unsigned int* cnt = (unsigned int*)(ws + WS_CNT);

    k_reset<<<1, 64, 0, stream>>>(cnt);
    mega<<<GRID_BLOCKS, 256, 0, stream>>>(ident, rem, h0, c0, emb, W_rin, b_rin,
                                          W_ih, W_hh, b_ih, b_hh, W_ro, b_ro,
                                          W_out, b_out, out, ws);
}

// Round 6
// 132.302 us; speedup vs baseline: 8.2344x; 8.2344x over previous
//
#include <hip/hip_runtime.h>
#include <math.h>

#define E_DIM 1024
#define H_DIM 2048
#define R_DIM 1024
#define RULES 50000

// d_out layout: [out 50000][h 2048][c 2048][remainder_out 1024]
#define OUT_H  50000
#define OUT_C  52048
#define OUT_RO 54096

// ws layout (float offsets); every write is a fixed slot -> deterministic
#define WS_XP    0          // [8][1024]    x partials (rem @ W_rin)
#define WS_GH    8192       // [8192]       ghh[j] = W_hh[j].h0 + b_hh[j]
#define WS_H     16384      // [2048]       h
#define WS_BSUM  18432      // [64]         per-block sum(exp(logit))
#define WS_CNT   18496      // [16] uints   k_tail spin counter (reset in k_pre)
#define WS_PL    18512      // [32][50000]  logits partials
#define WS_PRO   1618512    // [32][1024]   remainder_out partials

typedef float f32x4 __attribute__((ext_vector_type(4)));

__device__ __forceinline__ f32x4 nt4(const float* p) {
    return __builtin_nontemporal_load((const f32x4*)p);
}
__device__ __forceinline__ float sigf(float x) { return 1.f / (1.f + expf(-x)); }

// ---- Node 1: ghh = W_hh @ h0 + b_hh (2048 blocks); W_rin partials (32) -----
__global__ __launch_bounds__(256) void k_pre(const float* __restrict__ rem,
    const float* __restrict__ W_rin, const float* __restrict__ h0,
    const float* __restrict__ W_hh, const float* __restrict__ b_hh,
    float* __restrict__ xp, float* __restrict__ ghh,
    unsigned int* __restrict__ cnt)
{
    const int bid = blockIdx.x, tid = threadIdx.x;
    if (bid == 0 && tid == 0) *cnt = 0u;
    if (bid < 2048) {
        int w = tid >> 6, lane = tid & 63;
        int j = bid * 4 + w;                       // rows 0..8191 of W_hh
        const float* Wh = W_hh + (size_t)j * H_DIM;
        const f32x4* h4 = (const f32x4*)h0;
        float acc = 0.f;
#pragma unroll
        for (int s = 0; s < 8; ++s) {              // H/4 = 512 f32x4 over 64 lanes
            int idx = s * 64 + lane;
            f32x4 wv = nt4(Wh + idx * 4), hv = h4[idx];
            acc += wv.x * hv.x + wv.y * hv.y + wv.z * hv.z + wv.w * hv.w;
        }
#pragma unroll
        for (int off = 32; off > 0; off >>= 1) acc += __shfl_xor(acc, off);
        if (lane == 0) ghh[j] = acc + b_hh[j];
    } else {                                       // 32 blocks: W_rin partials
        __shared__ float rs[128];
        int b = bid - 2048;
        int ec = b & 3, rc = b >> 2;               // 4 e-chunks x 8 r-chunks
        if (tid < 128) rs[tid] = rem[rc * 128 + tid];
        __syncthreads();
        int e = ec * 256 + tid;
        const float* base = W_rin + (size_t)(rc * 128) * E_DIM + e;
        float acc = 0.f;
#pragma unroll 8
        for (int rr = 0; rr < 128; ++rr)
            acc = fmaf(rs[rr], __builtin_nontemporal_load(base + (size_t)rr * E_DIM), acc);
        xp[rc * E_DIM + e] = acc;
    }
}

// ---- Node 2: x = emb+relu(.); gates = W_ih@x + b_ih + ghh; cell math -------
__global__ __launch_bounds__(256) void k_lstm(const float* __restrict__ xp,
    const float* __restrict__ b_rin, const float* __restrict__ emb,
    const int* __restrict__ ident, const float* __restrict__ c0,
    const float* __restrict__ W_ih, const float* __restrict__ b_ih,
    const float* __restrict__ ghh, float* __restrict__ d_out,
    float* __restrict__ ws_h)
{
    __shared__ float xs[E_DIM];
    __shared__ float gl[4];
    const int tid = threadIdx.x, k = blockIdx.x;
    long long row = (long long)ident[0] * E_DIM;
    for (int e = tid; e < E_DIM; e += 256) {
        float s = 0.f;
#pragma unroll
        for (int rc = 0; rc < 8; ++rc) s += xp[rc * E_DIM + e];
        xs[e] = emb[row + e] + fmaxf(s + b_rin[e], 0.f);
    }
    __syncthreads();
    int w = tid >> 6, lane = tid & 63;
    int j = w * H_DIM + k;                         // torch gate order i,f,g,o
    const float* Wi = W_ih + (size_t)j * E_DIM;
    const f32x4* x4 = (const f32x4*)xs;
    float acc = 0.f;
#pragma unroll
    for (int s = 0; s < 4; ++s) {                  // E/4 = 256 f32x4 over 64 lanes
        int idx = s * 64 + lane;
        f32x4 wv = nt4(Wi + idx * 4), xv = x4[idx];
        acc += wv.x * xv.x + wv.y * xv.y + wv.z * xv.z + wv.w * xv.w;
    }
#pragma unroll
    for (int off = 32; off > 0; off >>= 1) acc += __shfl_xor(acc, off);
    if (lane == 0) gl[w] = acc + b_ih[j] + ghh[j];
    __syncthreads();
    if (tid == 0) {
        float gi = gl[0], gf = gl[1], gg = gl[2], go = gl[3];
        float c = sigf(gf) * c0[k] + sigf(gi) * tanhf(gg);
        float h = sigf(go) * tanhf(c);
        d_out[OUT_H + k] = h;
        d_out[OUT_C + k] = c;
        ws_h[k] = h;
    }
}

// ---- Node 3: partial GEMV tiles. bid<800: logits (jb=bid%25, 2048-wide,
//      hc=bid/25 chunk of 64 h); bid in [800,832): ro (hc=bid-800) -----------
__global__ __launch_bounds__(256) void k_big(const float* __restrict__ h,
    const float* __restrict__ W_out, const float* __restrict__ W_ro,
    float* __restrict__ pl, float* __restrict__ pro)
{
    __shared__ float hs[64];
    const int bid = blockIdx.x, tid = threadIdx.x;
    int hc = (bid < 800) ? (bid / 25) : (bid - 800);
    if (tid < 64) hs[tid] = h[hc * 64 + tid];
    __syncthreads();
    if (bid < 800) {
        int j0 = (bid % 25) * 2048 + tid * 8;
        if (j0 < RULES) {                          // RULES%8==0 -> full 8 valid
            f32x4 a0 = {0.f, 0.f, 0.f, 0.f}, a1 = {0.f, 0.f, 0.f, 0.f};
            const float* base = W_out + (size_t)(hc * 64) * RULES + j0;
#pragma unroll 8
            for (int hh = 0; hh < 64; ++hh) {
                float hv = hs[hh];
                f32x4 w0 = nt4(base + (size_t)hh * RULES);
                f32x4 w1 = nt4(base + (size_t)hh * RULES + 4);
                a0.x = fmaf(hv, w0.x, a0.x); a0.y = fmaf(hv, w0.y, a0.y);
                a0.z = fmaf(hv, w0.z, a0.z); a0.w = fmaf(hv, w0.w, a0.w);
                a1.x = fmaf(hv, w1.x, a1.x); a1.y = fmaf(hv, w1.y, a1.y);
                a1.z = fmaf(hv, w1.z, a1.z); a1.w = fmaf(hv, w1.w, a1.w);
            }
            *(f32x4*)(pl + (size_t)hc * RULES + j0) = a0;
            *(f32x4*)(pl + (size_t)hc * RULES + j0 + 4) = a1;
        }
    } else {
        int j0 = tid * 4;
        f32x4 acc = {0.f, 0.f, 0.f, 0.f};
        const float* base = W_ro + (size_t)(hc * 64) * R_DIM + j0;
#pragma unroll 16
        for (int hh = 0; hh < 64; ++hh) {
            float hv = hs[hh];
            f32x4 wv = nt4(base + (size_t)hh * R_DIM);
            acc.x = fmaf(hv, wv.x, acc.x); acc.y = fmaf(hv, wv.y, acc.y);
            acc.z = fmaf(hv, wv.z, acc.z); acc.w = fmaf(hv, wv.w, acc.w);
        }
        *(f32x4*)(pro + (size_t)hc * R_DIM + j0) = acc;
    }
}

// ---- Node 4: blocks 0..48 logits + mini-barrier + log_softmax; 49 -> ro ----
__global__ __launch_bounds__(256) void k_tail(const float* __restrict__ pl,
    const float* __restrict__ b_out, const float* __restrict__ pro,
    const float* __restrict__ b_ro, unsigned int* __restrict__ cnt,
    float* __restrict__ bsum, float* __restrict__ d_out)
{
    if (blockIdx.x == 49) {                        // remainder_out finalize
        int j0 = threadIdx.x * 4;
        f32x4 s = {0.f, 0.f, 0.f, 0.f};
#pragma unroll
        for (int hc = 0; hc < 32; ++hc) {
            f32x4 p = *(const f32x4*)(pro + (size_t)hc * R_DIM + j0);
            s.x += p.x; s.y += p.y; s.z += p.z; s.w += p.w;
        }
        const f32x4 b = *(const f32x4*)(b_ro + j0);
        f32x4 o;
        o.x = fmaxf(s.x + b.x, 0.f);
        o.y = fmaxf(s.y + b.y, 0.f);
        o.z = fmaxf(s.z + b.z, 0.f);
        o.w = fmaxf(s.w + b.w, 0.f);
        *(f32x4*)(d_out + OUT_RO + j0) = o;
        return;
    }
    int j0 = blockIdx.x * 1024 + threadIdx.x * 4;
    bool valid = j0 < RULES;
    f32x4 l = {0.f, 0.f, 0.f, 0.f};
    float se = 0.f;
    if (valid) {
        f32x4 s = {0.f, 0.f, 0.f, 0.f};
#pragma unroll
        for (int hc = 0; hc < 32; ++hc) {
            f32x4 p = *(const f32x4*)(pl + (size_t)hc * RULES + j0);
            s.x += p.x; s.y += p.y; s.z += p.z; s.w += p.w;
        }
        const f32x4 b = *(const f32x4*)(b_out + j0);
        l.x = fmaxf(s.x + b.x, 0.f);
        l.y = fmaxf(s.y + b.y, 0.f);
        l.z = fmaxf(s.z + b.z, 0.f);
        l.w = fmaxf(s.w + b.w, 0.f);
        se = expf(l.x) + expf(l.y) + expf(l.z) + expf(l.w);
    }
    __shared__ float red[256];
    red[threadIdx.x] = se;
    __syncthreads();
    for (int off = 128; off > 0; off >>= 1) {
        if (threadIdx.x < off) red[threadIdx.x] += red[threadIdx.x + off];
        __syncthreads();
    }
    __shared__ float lse_s;
    if (threadIdx.x == 0) {
        bsum[blockIdx.x] = red[0];
        __threadfence();
        __hip_atomic_fetch_add(cnt, 1u, __ATOMIC_RELEASE, __HIP_MEMORY_SCOPE_AGENT);
        // 49 blocks << 256 CUs: co-resident, safe to spin
        while (__hip_atomic_load(cnt, __ATOMIC_ACQUIRE, __HIP_MEMORY_SCOPE_AGENT) < 49u) {}
        float ssum = 0.f;
        for (int i = 0; i < 49; ++i) ssum += bsum[i];  // fixed order: deterministic
        lse_s = logf(ssum);
    }
    __syncthreads();
    if (valid) {
        f32x4 o = {l.x - lse_s, l.y - lse_s, l.z - lse_s, l.w - lse_s};
        *(f32x4*)(d_out + j0) = o;
    }
}

extern "C" void kernel_launch(void* const* d_in, const int* in_sizes, int n_in,
                              void* d_out, int out_size, void* d_ws, size_t ws_size,
                              hipStream_t stream)
{
    const int*   ident = (const int*)  d_in[0];
    const float* rem   = (const float*)d_in[1];
    const float* h0    = (const float*)d_in[2];
    const float* c0    = (const float*)d_in[3];
    const float* emb   = (const float*)d_in[4];
    const float* W_rin = (const float*)d_in[5];
    const float* b_rin = (const float*)d_in[6];
    const float* W_ih  = (const float*)d_in[7];
    const float* W_hh  = (const float*)d_in[8];
    const float* b_ih  = (const float*)d_in[9];
    const float* b_hh  = (const float*)d_in[10];
    const float* W_ro  = (const float*)d_in[11];
    const float* b_ro  = (const float*)d_in[12];
    const float* W_out = (const float*)d_in[13];
    const float* b_out = (const float*)d_in[14];
    float* out = (float*)d_out;
    float* ws  = (float*)d_ws;
    unsigned int* cnt = (unsigned int*)(ws + WS_CNT);

    k_pre<<<2080, 256, 0, stream>>>(rem, W_rin, h0, W_hh, b_hh,
                                    ws + WS_XP, ws + WS_GH, cnt);
    k_lstm<<<2048, 256, 0, stream>>>(ws + WS_XP, b_rin, emb, ident, c0,
                                     W_ih, b_ih, ws + WS_GH, out, ws + WS_H);
    k_big<<<832, 256, 0, stream>>>(ws + WS_H, W_out, W_ro,
                                   ws + WS_PL, ws + WS_PRO);
    k_tail<<<50, 256, 0, stream>>>(ws + WS_PL, b_out, ws + WS_PRO, b_ro,
                                   cnt, ws + WS_BSUM, out);
}

// Round 7
// 113.594 us; speedup vs baseline: 9.5905x; 1.1647x over previous
//
#include <hip/hip_runtime.h>
#include <math.h>

#define E_DIM 1024
#define H_DIM 2048
#define R_DIM 1024
#define RULES 50000

// d_out layout: [out 50000][h 2048][c 2048][remainder_out 1024]
#define OUT_H  50000
#define OUT_C  52048
#define OUT_RO 54096

// ws layout (float offsets); every write is a fixed slot -> deterministic
#define WS_XP    0          // [8][1024]    x partials (rem @ W_rin)
#define WS_GH    8192       // [8192]       ghh[j] = W_hh[j].h0 + b_hh[j]
#define WS_H     16384      // [2048]       h
#define WS_BSUM  18432      // [64]         per-block sum(exp(logit))
#define WS_CNT   18496      // [16] uints   k_tail spin counter (reset in k_pre)
#define WS_PL    18512      // [32][50000]  logits partials
#define WS_PRO   1618512    // [32][1024]   remainder_out partials

typedef float f32x4 __attribute__((ext_vector_type(4)));

__device__ __forceinline__ f32x4 nt4(const float* p) {
    return __builtin_nontemporal_load((const f32x4*)p);
}
__device__ __forceinline__ float sigf(float x) { return 1.f / (1.f + expf(-x)); }

// ---- Node 1: ghh = W_hh @ h0 + b_hh (2048 blocks); W_rin partials (32) -----
__global__ __launch_bounds__(256) void k_pre(const float* __restrict__ rem,
    const float* __restrict__ W_rin, const float* __restrict__ h0,
    const float* __restrict__ W_hh, const float* __restrict__ b_hh,
    float* __restrict__ xp, float* __restrict__ ghh,
    unsigned int* __restrict__ cnt)
{
    const int bid = blockIdx.x, tid = threadIdx.x;
    if (bid == 0 && tid == 0) *cnt = 0u;
    if (bid < 2048) {
        int w = tid >> 6, lane = tid & 63;
        int j = bid * 4 + w;                       // rows 0..8191 of W_hh
        const float* Wh = W_hh + (size_t)j * H_DIM;
        const f32x4* h4 = (const f32x4*)h0;
        float acc = 0.f;
#pragma unroll
        for (int s = 0; s < 8; ++s) {              // H/4 = 512 f32x4 over 64 lanes
            int idx = s * 64 + lane;
            f32x4 wv = nt4(Wh + idx * 4), hv = h4[idx];
            acc += wv.x * hv.x + wv.y * hv.y + wv.z * hv.z + wv.w * hv.w;
        }
#pragma unroll
        for (int off = 32; off > 0; off >>= 1) acc += __shfl_xor(acc, off);
        if (lane == 0) ghh[j] = acc + b_hh[j];
    } else {                                       // 32 blocks: W_rin partials
        __shared__ float rs[128];
        int b = bid - 2048;
        int ec = b & 3, rc = b >> 2;               // 4 e-chunks x 8 r-chunks
        if (tid < 128) rs[tid] = rem[rc * 128 + tid];
        __syncthreads();
        int e = ec * 256 + tid;
        const float* base = W_rin + (size_t)(rc * 128) * E_DIM + e;
        float acc = 0.f;
#pragma unroll 8
        for (int rr = 0; rr < 128; ++rr)
            acc = fmaf(rs[rr], __builtin_nontemporal_load(base + (size_t)rr * E_DIM), acc);
        xp[rc * E_DIM + e] = acc;
    }
}

// ---- Node 2: x = emb+relu(.); gates = W_ih@x + b_ih + ghh; cell math -------
__global__ __launch_bounds__(256) void k_lstm(const float* __restrict__ xp,
    const float* __restrict__ b_rin, const float* __restrict__ emb,
    const int* __restrict__ ident, const float* __restrict__ c0,
    const float* __restrict__ W_ih, const float* __restrict__ b_ih,
    const float* __restrict__ ghh, float* __restrict__ d_out,
    float* __restrict__ ws_h)
{
    __shared__ float xs[E_DIM];
    __shared__ float gl[4];
    const int tid = threadIdx.x, k = blockIdx.x;
    long long row = (long long)ident[0] * E_DIM;
    for (int e = tid; e < E_DIM; e += 256) {
        float s = 0.f;
#pragma unroll
        for (int rc = 0; rc < 8; ++rc) s += xp[rc * E_DIM + e];
        xs[e] = emb[row + e] + fmaxf(s + b_rin[e], 0.f);
    }
    __syncthreads();
    int w = tid >> 6, lane = tid & 63;
    int j = w * H_DIM + k;                         // torch gate order i,f,g,o
    const float* Wi = W_ih + (size_t)j * E_DIM;
    const f32x4* x4 = (const f32x4*)xs;
    float acc = 0.f;
#pragma unroll
    for (int s = 0; s < 4; ++s) {                  // E/4 = 256 f32x4 over 64 lanes
        int idx = s * 64 + lane;
        f32x4 wv = nt4(Wi + idx * 4), xv = x4[idx];
        acc += wv.x * xv.x + wv.y * xv.y + wv.z * xv.z + wv.w * xv.w;
    }
#pragma unroll
    for (int off = 32; off > 0; off >>= 1) acc += __shfl_xor(acc, off);
    if (lane == 0) gl[w] = acc + b_ih[j] + ghh[j];
    __syncthreads();
    if (tid == 0) {
        float gi = gl[0], gf = gl[1], gg = gl[2], go = gl[3];
        float c = sigf(gf) * c0[k] + sigf(gi) * tanhf(gg);
        float h = sigf(go) * tanhf(c);
        d_out[OUT_H + k] = h;
        d_out[OUT_C + k] = c;
        ws_h[k] = h;
    }
}

// ---- Node 3 (R3-proven): grid (50,32); x<49 logits 1024-wide, x==49 ro -----
__global__ __launch_bounds__(256) void k_big(const float* __restrict__ h,
    const float* __restrict__ W_out, const float* __restrict__ W_ro,
    float* __restrict__ pl, float* __restrict__ pro)
{
    __shared__ float hs[64];
    int hc = blockIdx.y;                       // 0..31, chunk of 64 h
    if (threadIdx.x < 64) hs[threadIdx.x] = h[hc * 64 + threadIdx.x];
    __syncthreads();
    if (blockIdx.x < 49) {
        int j0 = blockIdx.x * 1024 + threadIdx.x * 4;
        if (j0 >= RULES) return;
        f32x4 acc = {0.f, 0.f, 0.f, 0.f};
        const float* base = W_out + (size_t)hc * 64 * RULES + j0;
#pragma unroll 16
        for (int hh = 0; hh < 64; ++hh) {
            float hv = hs[hh];
            f32x4 wv = nt4(base + (size_t)hh * RULES);
            acc.x = fmaf(hv, wv.x, acc.x);
            acc.y = fmaf(hv, wv.y, acc.y);
            acc.z = fmaf(hv, wv.z, acc.z);
            acc.w = fmaf(hv, wv.w, acc.w);
        }
        *(f32x4*)(pl + (size_t)hc * RULES + j0) = acc;
    } else {
        int j0 = threadIdx.x * 4;
        f32x4 acc = {0.f, 0.f, 0.f, 0.f};
        const float* base = W_ro + (size_t)hc * 64 * R_DIM + j0;
#pragma unroll 16
        for (int hh = 0; hh < 64; ++hh) {
            float hv = hs[hh];
            f32x4 wv = nt4(base + (size_t)hh * R_DIM);
            acc.x = fmaf(hv, wv.x, acc.x);
            acc.y = fmaf(hv, wv.y, acc.y);
            acc.z = fmaf(hv, wv.z, acc.z);
            acc.w = fmaf(hv, wv.w, acc.w);
        }
        *(f32x4*)(pro + (size_t)hc * R_DIM + j0) = acc;
    }
}

// ---- Node 4 (R3-proven): blocks 0..48 logits + mini-spin + lse; 49 -> ro ---
__global__ __launch_bounds__(256) void k_tail(const float* __restrict__ pl,
    const float* __restrict__ b_out, const float* __restrict__ pro,
    const float* __restrict__ b_ro, unsigned int* __restrict__ cnt,
    float* __restrict__ bsum, float* __restrict__ d_out)
{
    if (blockIdx.x == 49) {                    // remainder_out finalize
        int j0 = threadIdx.x * 4;
        f32x4 s = {0.f, 0.f, 0.f, 0.f};
#pragma unroll
        for (int hc = 0; hc < 32; ++hc) {
            f32x4 p = *(const f32x4*)(pro + (size_t)hc * R_DIM + j0);
            s.x += p.x; s.y += p.y; s.z += p.z; s.w += p.w;
        }
        const f32x4 b = *(const f32x4*)(b_ro + j0);
        f32x4 o;
        o.x = fmaxf(s.x + b.x, 0.f);
        o.y = fmaxf(s.y + b.y, 0.f);
        o.z = fmaxf(s.z + b.z, 0.f);
        o.w = fmaxf(s.w + b.w, 0.f);
        *(f32x4*)(d_out + OUT_RO + j0) = o;
        return;
    }
    int j0 = blockIdx.x * 1024 + threadIdx.x * 4;
    bool valid = j0 < RULES;
    f32x4 l = {0.f, 0.f, 0.f, 0.f};
    float se = 0.f;
    if (valid) {
        f32x4 s = {0.f, 0.f, 0.f, 0.f};
#pragma unroll
        for (int hc = 0; hc < 32; ++hc) {
            f32x4 p = *(const f32x4*)(pl + (size_t)hc * RULES + j0);
            s.x += p.x; s.y += p.y; s.z += p.z; s.w += p.w;
        }
        const f32x4 b = *(const f32x4*)(b_out + j0);
        l.x = fmaxf(s.x + b.x, 0.f);
        l.y = fmaxf(s.y + b.y, 0.f);
        l.z = fmaxf(s.z + b.z, 0.f);
        l.w = fmaxf(s.w + b.w, 0.f);
        se = expf(l.x) + expf(l.y) + expf(l.z) + expf(l.w);
    }
    __shared__ float red[256];
    red[threadIdx.x] = se;
    __syncthreads();
    for (int off = 128; off > 0; off >>= 1) {
        if (threadIdx.x < off) red[threadIdx.x] += red[threadIdx.x + off];
        __syncthreads();
    }
    __shared__ float lse_s;
    if (threadIdx.x == 0) {
        bsum[blockIdx.x] = red[0];
        __threadfence();
        __hip_atomic_fetch_add(cnt, 1u, __ATOMIC_RELEASE, __HIP_MEMORY_SCOPE_AGENT);
        // 49 blocks << 256 CUs: co-resident, safe to spin
        while (__hip_atomic_load(cnt, __ATOMIC_ACQUIRE, __HIP_MEMORY_SCOPE_AGENT) < 49u) {}
        float ssum = 0.f;
        for (int i = 0; i < 49; ++i) ssum += bsum[i];  // fixed order: deterministic
        lse_s = logf(ssum);
    }
    __syncthreads();
    if (valid) {
        f32x4 o = {l.x - lse_s, l.y - lse_s, l.z - lse_s, l.w - lse_s};
        *(f32x4*)(d_out + j0) = o;
    }
}

extern "C" void kernel_launch(void* const* d_in, const int* in_sizes, int n_in,
                              void* d_out, int out_size, void* d_ws, size_t ws_size,
                              hipStream_t stream)
{
    const int*   ident = (const int*)  d_in[0];
    const float* rem   = (const float*)d_in[1];
    const float* h0    = (const float*)d_in[2];
    const float* c0    = (const float*)d_in[3];
    const float* emb   = (const float*)d_in[4];
    const float* W_rin = (const float*)d_in[5];
    const float* b_rin = (const float*)d_in[6];
    const float* W_ih  = (const float*)d_in[7];
    const float* W_hh  = (const float*)d_in[8];
    const float* b_ih  = (const float*)d_in[9];
    const float* b_hh  = (const float*)d_in[10];
    const float* W_ro  = (const float*)d_in[11];
    const float* b_ro  = (const float*)d_in[12];
    const float* W_out = (const float*)d_in[13];
    const float* b_out = (const float*)d_in[14];
    float* out = (float*)d_out;
    float* ws  = (float*)d_ws;
    unsigned int* cnt = (unsigned int*)(ws + WS_CNT);

    k_pre<<<2080, 256, 0, stream>>>(rem, W_rin, h0, W_hh, b_hh,
                                    ws + WS_XP, ws + WS_GH, cnt);
    k_lstm<<<2048, 256, 0, stream>>>(ws + WS_XP, b_rin, emb, ident, c0,
                                     W_ih, b_ih, ws + WS_GH, out, ws + WS_H);
    k_big<<<dim3(50, 32), 256, 0, stream>>>(ws + WS_H, W_out, W_ro,
                                            ws + WS_PL, ws + WS_PRO);
    k_tail<<<50, 256, 0, stream>>>(ws + WS_PL, b_out, ws + WS_PRO, b_ro,
                                   cnt, ws + WS_BSUM, out);
}

// Round 8
// 112.889 us; speedup vs baseline: 9.6504x; 1.0062x over previous
//
#include <hip/hip_runtime.h>
#include <math.h>

#define E_DIM 1024
#define H_DIM 2048
#define R_DIM 1024
#define RULES 50000

// d_out layout: [out 50000][h 2048][c 2048][remainder_out 1024]
#define OUT_H  50000
#define OUT_C  52048
#define OUT_RO 54096

// ws layout (float offsets); every write is a fixed slot -> deterministic
#define WS_XP    0          // [8][1024]    x partials (rem @ W_rin)
#define WS_H     8192       // [2048]       h
#define WS_BSUM  10240      // [64]         per-block sum(exp(logit))
#define WS_CNT   10304      // [16] uints   k_tail spin counter (reset in node 1)
#define WS_PL    10320      // [32][50000]  logits partials
#define WS_PRO   1610320    // [32][1024]   remainder_out partials

typedef float f32x4 __attribute__((ext_vector_type(4)));

__device__ __forceinline__ f32x4 nt4(const float* p) {
    return __builtin_nontemporal_load((const f32x4*)p);
}
__device__ __forceinline__ float sigf(float x) { return 1.f / (1.f + expf(-x)); }

// ---- Node 1 (R3-proven): xp[rc][e] partials of rem @ W_rin (32 blocks) -----
__global__ __launch_bounds__(256) void k_x_partial(const float* __restrict__ rem,
    const float* __restrict__ W_rin, float* __restrict__ xp,
    unsigned int* __restrict__ cnt)
{
    if (blockIdx.x == 0 && blockIdx.y == 0 && threadIdx.x == 0) *cnt = 0u;
    __shared__ float rs[128];
    int ec = blockIdx.x, rc = blockIdx.y;
    if (threadIdx.x < 128) rs[threadIdx.x] = rem[rc * 128 + threadIdx.x];
    __syncthreads();
    int e = ec * 256 + threadIdx.x;
    const float* base = W_rin + (size_t)rc * 128 * E_DIM + e;
    float acc = 0.f;
#pragma unroll 8
    for (int rr = 0; rr < 128; ++rr)
        acc = fmaf(rs[rr], __builtin_nontemporal_load(base + (size_t)rr * E_DIM), acc);
    xp[rc * E_DIM + e] = acc;
}

// ---- Node 2 (R3-proven): LSTM, block k; 4 waves = gates i,f,g,o ------------
__global__ __launch_bounds__(256) void k_lstm(const float* __restrict__ xp,
    const float* __restrict__ b_rin, const float* __restrict__ emb,
    const int* __restrict__ ident,
    const float* __restrict__ h0, const float* __restrict__ c0,
    const float* __restrict__ W_ih, const float* __restrict__ W_hh,
    const float* __restrict__ b_ih, const float* __restrict__ b_hh,
    float* __restrict__ d_out, float* __restrict__ ws_h)
{
    __shared__ float xs[E_DIM];
    __shared__ float gl[4];
    const int tid = threadIdx.x, k = blockIdx.x;
    long long row = (long long)ident[0] * E_DIM;
    for (int e = tid; e < E_DIM; e += 256) {
        float s = 0.f;
#pragma unroll
        for (int rc = 0; rc < 8; ++rc) s += xp[rc * E_DIM + e];
        xs[e] = emb[row + e] + fmaxf(s + b_rin[e], 0.f);
    }
    __syncthreads();
    int w = tid >> 6, lane = tid & 63;
    int j = w * H_DIM + k;                         // torch gate order i,f,g,o
    const float* Wi = W_ih + (size_t)j * E_DIM;
    const float* Wh = W_hh + (size_t)j * H_DIM;
    const f32x4* x4 = (const f32x4*)xs;
    const f32x4* h4 = (const f32x4*)h0;
    float acc = 0.f;
#pragma unroll
    for (int s = 0; s < 4; ++s) {                  // E/4 = 256 f32x4 over 64 lanes
        int idx = s * 64 + lane;
        f32x4 wv = nt4(Wi + idx * 4), xv = x4[idx];
        acc += wv.x * xv.x + wv.y * xv.y + wv.z * xv.z + wv.w * xv.w;
    }
#pragma unroll
    for (int s = 0; s < 8; ++s) {                  // H/4 = 512 f32x4
        int idx = s * 64 + lane;
        f32x4 wv = nt4(Wh + idx * 4), hv = h4[idx];
        acc += wv.x * hv.x + wv.y * hv.y + wv.z * hv.z + wv.w * hv.w;
    }
#pragma unroll
    for (int off = 32; off > 0; off >>= 1) acc += __shfl_xor(acc, off);
    if (lane == 0) gl[w] = acc + b_ih[j] + b_hh[j];
    __syncthreads();
    if (tid == 0) {
        float gi = gl[0], gf = gl[1], gg = gl[2], go = gl[3];
        float c = sigf(gf) * c0[k] + sigf(gi) * tanhf(gg);
        float h = sigf(go) * tanhf(c);
        d_out[OUT_H + k] = h;
        d_out[OUT_C + k] = c;
        ws_h[k] = h;
    }
}

// ---- Node 3: 2048 blocks (8/CU exact). bid<2016: logits (jt=bid%63 tile of
//      800 j, hc=bid/63 chunk of 64 h, threads 0..199 x 4 contiguous floats);
//      bid>=2016: ro (hc=bid-2016). Same pl/pro layout as R3. ----------------
__global__ __launch_bounds__(256) void k_big(const float* __restrict__ h,
    const float* __restrict__ W_out, const float* __restrict__ W_ro,
    float* __restrict__ pl, float* __restrict__ pro)
{
    __shared__ float hs[64];
    const int bid = blockIdx.x, tid = threadIdx.x;
    int hc = (bid < 2016) ? (bid / 63) : (bid - 2016);
    if (tid < 64) hs[tid] = h[hc * 64 + tid];
    __syncthreads();
    if (bid < 2016) {
        int jc = tid * 4;                          // offset within the 800-j tile
        int j0 = (bid % 63) * 800 + jc;
        if (jc < 800 && j0 < RULES) {
            f32x4 acc = {0.f, 0.f, 0.f, 0.f};
            const float* base = W_out + (size_t)(hc * 64) * RULES + j0;
#pragma unroll 16
            for (int hh = 0; hh < 64; ++hh) {
                float hv = hs[hh];
                f32x4 wv = nt4(base + (size_t)hh * RULES);
                acc.x = fmaf(hv, wv.x, acc.x);
                acc.y = fmaf(hv, wv.y, acc.y);
                acc.z = fmaf(hv, wv.z, acc.z);
                acc.w = fmaf(hv, wv.w, acc.w);
            }
            *(f32x4*)(pl + (size_t)hc * RULES + j0) = acc;
        }
    } else {
        int j0 = tid * 4;
        f32x4 acc = {0.f, 0.f, 0.f, 0.f};
        const float* base = W_ro + (size_t)(hc * 64) * R_DIM + j0;
#pragma unroll 16
        for (int hh = 0; hh < 64; ++hh) {
            float hv = hs[hh];
            f32x4 wv = nt4(base + (size_t)hh * R_DIM);
            acc.x = fmaf(hv, wv.x, acc.x);
            acc.y = fmaf(hv, wv.y, acc.y);
            acc.z = fmaf(hv, wv.z, acc.z);
            acc.w = fmaf(hv, wv.w, acc.w);
        }
        *(f32x4*)(pro + (size_t)hc * R_DIM + j0) = acc;
    }
}

// ---- Node 4 (R3-proven): blocks 0..48 logits + mini-spin + lse; 49 -> ro ---
__global__ __launch_bounds__(256) void k_tail(const float* __restrict__ pl,
    const float* __restrict__ b_out, const float* __restrict__ pro,
    const float* __restrict__ b_ro, unsigned int* __restrict__ cnt,
    float* __restrict__ bsum, float* __restrict__ d_out)
{
    if (blockIdx.x == 49) {                        // remainder_out finalize
        int j0 = threadIdx.x * 4;
        f32x4 s = {0.f, 0.f, 0.f, 0.f};
#pragma unroll
        for (int hc = 0; hc < 32; ++hc) {
            f32x4 p = *(const f32x4*)(pro + (size_t)hc * R_DIM + j0);
            s.x += p.x; s.y += p.y; s.z += p.z; s.w += p.w;
        }
        const f32x4 b = *(const f32x4*)(b_ro + j0);
        f32x4 o;
        o.x = fmaxf(s.x + b.x, 0.f);
        o.y = fmaxf(s.y + b.y, 0.f);
        o.z = fmaxf(s.z + b.z, 0.f);
        o.w = fmaxf(s.w + b.w, 0.f);
        *(f32x4*)(d_out + OUT_RO + j0) = o;
        return;
    }
    int j0 = blockIdx.x * 1024 + threadIdx.x * 4;
    bool valid = j0 < RULES;
    f32x4 l = {0.f, 0.f, 0.f, 0.f};
    float se = 0.f;
    if (valid) {
        f32x4 s = {0.f, 0.f, 0.f, 0.f};
#pragma unroll
        for (int hc = 0; hc < 32; ++hc) {
            f32x4 p = *(const f32x4*)(pl + (size_t)hc * RULES + j0);
            s.x += p.x; s.y += p.y; s.z += p.z; s.w += p.w;
        }
        const f32x4 b = *(const f32x4*)(b_out + j0);
        l.x = fmaxf(s.x + b.x, 0.f);
        l.y = fmaxf(s.y + b.y, 0.f);
        l.z = fmaxf(s.z + b.z, 0.f);
        l.w = fmaxf(s.w + b.w, 0.f);
        se = expf(l.x) + expf(l.y) + expf(l.z) + expf(l.w);
    }
    __shared__ float red[256];
    red[threadIdx.x] = se;
    __syncthreads();
    for (int off = 128; off > 0; off >>= 1) {
        if (threadIdx.x < off) red[threadIdx.x] += red[threadIdx.x + off];
        __syncthreads();
    }
    __shared__ float lse_s;
    if (threadIdx.x == 0) {
        bsum[blockIdx.x] = red[0];
        __threadfence();
        __hip_atomic_fetch_add(cnt, 1u, __ATOMIC_RELEASE, __HIP_MEMORY_SCOPE_AGENT);
        // 49 blocks << 256 CUs: co-resident, safe to spin
        while (__hip_atomic_load(cnt, __ATOMIC_ACQUIRE, __HIP_MEMORY_SCOPE_AGENT) < 49u) {}
        float ssum = 0.f;
        for (int i = 0; i < 49; ++i) ssum += bsum[i];  // fixed order: deterministic
        lse_s = logf(ssum);
    }
    __syncthreads();
    if (valid) {
        f32x4 o = {l.x - lse_s, l.y - lse_s, l.z - lse_s, l.w - lse_s};
        *(f32x4*)(d_out + j0) = o;
    }
}

extern "C" void kernel_launch(void* const* d_in, const int* in_sizes, int n_in,
                              void* d_out, int out_size, void* d_ws, size_t ws_size,
                              hipStream_t stream)
{
    const int*   ident = (const int*)  d_in[0];
    const float* rem   = (const float*)d_in[1];
    const float* h0    = (const float*)d_in[2];
    const float* c0    = (const float*)d_in[3];
    const float* emb   = (const float*)d_in[4];
    const float* W_rin = (const float*)d_in[5];
    const float* b_rin = (const float*)d_in[6];
    const float* W_ih  = (const float*)d_in[7];
    const float* W_hh  = (const float*)d_in[8];
    const float* b_ih  = (const float*)d_in[9];
    const float* b_hh  = (const float*)d_in[10];
    const float* W_ro  = (const float*)d_in[11];
    const float* b_ro  = (const float*)d_in[12];
    const float* W_out = (const float*)d_in[13];
    const float* b_out = (const float*)d_in[14];
    float* out = (float*)d_out;
    float* ws  = (float*)d_ws;
    unsigned int* cnt = (unsigned int*)(ws + WS_CNT);

    k_x_partial<<<dim3(4, 8), 256, 0, stream>>>(rem, W_rin, ws + WS_XP, cnt);
    k_lstm<<<2048, 256, 0, stream>>>(ws + WS_XP, b_rin, emb, ident,
                                     h0, c0, W_ih, W_hh, b_ih, b_hh,
                                     out, ws + WS_H);
    k_big<<<2048, 256, 0, stream>>>(ws + WS_H, W_out, W_ro,
                                    ws + WS_PL, ws + WS_PRO);
    k_tail<<<50, 256, 0, stream>>>(ws + WS_PL, b_out, ws + WS_PRO, b_ro,
                                   cnt, ws + WS_BSUM, out);
}